// Round 1
// baseline (658.225 us; speedup 1.0000x reference)
//
#include <hip/hip_runtime.h>

typedef unsigned short u16;
typedef unsigned int u32;

// Problem constants
static constexpr int B = 16, C = 32, H = 192, W = 192;
static constexpr int HW = H * W;              // 36864
static constexpr int E = 8;                   // experts
static constexpr int CO = 32;
static constexpr long long NTOT = (long long)B * C * HW; // 18874368
static constexpr float SILU1 = 0.7310585786300049f;      // silu(1) for P0 block

// Workspace layout (bytes)
static constexpr size_t T_OFF  = 0;                          // bf16 tanh(x), NTOT elems
static constexpr size_t GX_OFF = (size_t)NTOT * 2;           // gate_x: 512 floats
static constexpr size_t SC_OFF = GX_OFF + 512 * 4;           // scale: 16 floats
static constexpr size_t SK_OFF = SC_OFF + 16 * 4;            // Sk: 288 floats [k][co]

__device__ inline u16 f2b(float f) {             // rne float->bf16 bits
    u32 u = __float_as_uint(f);
    return (u16)((u + 0x7fffu + ((u >> 16) & 1u)) >> 16);
}
__device__ inline float b2f(u16 r) { return __uint_as_float((u32)r << 16); }
__device__ inline float silu(float z) { return z / (1.0f + __expf(-z)); }

// ---------------- Stage 1: t = tanh(x) (bf16) + per-(b,c) mean for gating ----
__global__ __launch_bounds__(256) void stage1(const float* __restrict__ x,
                                              u16* __restrict__ t_out,
                                              float* __restrict__ gate_x) {
    const int bc = blockIdx.x;                    // (b*32+c), one block per plane
    const float4* xp = (const float4*)(x + (size_t)bc * HW);
    ushort4* tp = (ushort4*)(t_out + (size_t)bc * HW);
    float s = 0.0f;
    for (int i = threadIdx.x; i < HW / 4; i += 256) {
        float4 v = xp[i];
        s += (v.x + v.y) + (v.z + v.w);
        ushort4 o;
        o.x = f2b(tanhf(v.x)); o.y = f2b(tanhf(v.y));
        o.z = f2b(tanhf(v.z)); o.w = f2b(tanhf(v.w));
        tp[i] = o;
    }
    // wave64 reduce then cross-wave
    for (int off = 32; off > 0; off >>= 1) s += __shfl_down(s, off, 64);
    __shared__ float red[4];
    const int lane = threadIdx.x & 63, wv = threadIdx.x >> 6;
    if (lane == 0) red[wv] = s;
    __syncthreads();
    if (threadIdx.x == 0)
        gate_x[bc] = (red[0] + red[1] + red[2] + red[3]) * (1.0f / HW);
}

// ---------------- Stage 2: gating, loss, scale[b], Sk sums ------------------
__global__ __launch_bounds__(256) void gating(const float* __restrict__ gate_x,
                                              const float* __restrict__ wg,   // (32,8)
                                              const float* __restrict__ pw,   // (32,128,3,3)
                                              float* __restrict__ scale,
                                              float* __restrict__ Sk,
                                              float* __restrict__ loss_out) {
    const int t = threadIdx.x;
    // Sk[k][co] = sum_{ci<32} W[co][ci][k]  (P0-block weight sums)
    for (int j = t; j < 288; j += 256) {
        int k = j >> 5, co = j & 31;
        float s = 0.0f;
        for (int ci = 0; ci < 32; ++ci) s += pw[(size_t)co * 1152 + ci * 9 + k];
        Sk[j] = s;
    }
    __shared__ float gsh[B][E];
    if (t < B) {
        float logits[E];
        for (int e = 0; e < E; ++e) {
            float s = 0.0f;
            for (int c = 0; c < C; ++c) s += gate_x[t * C + c] * wg[c * E + e];
            logits[e] = s;
        }
        float m = logits[0];
        for (int e = 1; e < E; ++e) m = fmaxf(m, logits[e]);
        float p[E], sum = 0.0f;
        for (int e = 0; e < E; ++e) { p[e] = expf(logits[e] - m); sum += p[e]; }
        for (int e = 0; e < E; ++e) p[e] /= sum;
        // top-2, ties -> lowest index (matches jax.lax.top_k; 3rd value unused)
        int i0 = 0; float v0 = p[0];
        for (int e = 1; e < E; ++e) if (p[e] > v0) { v0 = p[e]; i0 = e; }
        int i1 = -1; float v1 = -1.0f;
        for (int e = 0; e < E; ++e) { if (e == i0) continue; if (p[e] > v1) { v1 = p[e]; i1 = e; } }
        const float denom = v0 + v1 + 1e-6f;
        const float g0 = v0 / denom, g1 = v1 / denom;
        for (int e = 0; e < E; ++e) gsh[t][e] = 0.0f;
        gsh[t][i0] = g0; gsh[t][i1] = g1;
        scale[t] = g0 + g1;
    }
    __syncthreads();
    __shared__ float impsh[E], loadsh[E];
    if (t < E) {
        float imp = 0.0f, ld = 0.0f;
        for (int b = 0; b < B; ++b) {
            float g = gsh[b][t];
            imp += g;
            if (g > 0.0f) ld += 1.0f;
        }
        impsh[t] = imp; loadsh[t] = ld;
    }
    __syncthreads();
    if (t == 0) {
        float mi = 0.0f, ml = 0.0f;
        for (int e = 0; e < E; ++e) { mi += impsh[e]; ml += loadsh[e]; }
        mi *= (1.0f / E); ml *= (1.0f / E);
        float vi = 0.0f, vl = 0.0f;
        for (int e = 0; e < E; ++e) {
            float di = impsh[e] - mi, dl = loadsh[e] - ml;
            vi += di * di; vl += dl * dl;
        }
        vi *= (1.0f / (E - 1)); vl *= (1.0f / (E - 1));
        *loss_out = (vi / (mi * mi + 1e-10f) + vl / (ml * ml + 1e-10f)) * 0.01f;
    }
}

// ---------------- Stage 3: fused gram-basis + silu + 3x3 conv + scale -------
// Tile: 32(w) x 16(h) spatial, all 32 co. 256 thr = 4 co-groups x 64 lanes.
// Thread: 2y x 4x positions x 8 co = 64 accumulators, patch in registers.
static constexpr int TW = 32, TH = 16;
static constexpr int GC = 36;            // g_s row stride (34 used, padded to x4)
static constexpr int GR = TH + 2;        // 18 rows
static constexpr int GP = GR * GC;       // 648 floats plane stride
static constexpr int NPL = 12;           // planes per chunk: 4 base c x 3 poly

__global__ __launch_bounds__(256) void conv_kernel(const u16* __restrict__ t_ws,
                                                   const float* __restrict__ pw,
                                                   const float* __restrict__ beta_w,
                                                   const float* __restrict__ scale,
                                                   const float* __restrict__ Sk,
                                                   float* __restrict__ out) {
    __shared__ __align__(16) float g_s[NPL * GP];      // 31104 B
    __shared__ __align__(16) float w_s[NPL * 9 * 32];  // 13824 B  [lp][k][co]
    __shared__ __align__(16) float sk_s[288];          // [k][co]

    const int b = blockIdx.z;
    const int gx0t = blockIdx.x * TW;   // 0..160
    const int gy0t = blockIdx.y * TH;   // 0..176
    const int tid = threadIdx.x;
    const int co0 = (tid >> 6) * 8;     // wave-uniform
    const int lane = tid & 63;
    const int x0 = (lane & 7) * 4;      // 0..28
    const int y0 = (lane >> 3) * 2;     // 0..14

    const float beta2 = 2.25f * beta_w[1];
    const float beta3 = (300.0f / 9.0f) * beta_w[2];

    for (int j = tid; j < 288; j += 256) sk_s[j] = Sk[j];
    __syncthreads();

    float acc[2][4][8];
    #pragma unroll
    for (int ry = 0; ry < 2; ++ry)
        #pragma unroll
        for (int rx = 0; rx < 4; ++rx)
            #pragma unroll
            for (int co = 0; co < 8; ++co) acc[ry][rx][co] = 0.0f;

    // P0-block bias: 0.731 * sum over valid taps of Sk
    #pragma unroll
    for (int k = 0; k < 9; ++k) {
        const int kh = k / 3, kw = k - kh * 3;
        float4 wa = *(const float4*)&sk_s[k * 32 + co0];
        float4 wb = *(const float4*)&sk_s[k * 32 + co0 + 4];
        float wv[8] = {wa.x * SILU1, wa.y * SILU1, wa.z * SILU1, wa.w * SILU1,
                       wb.x * SILU1, wb.y * SILU1, wb.z * SILU1, wb.w * SILU1};
        #pragma unroll
        for (int ry = 0; ry < 2; ++ry)
            #pragma unroll
            for (int rx = 0; rx < 4; ++rx) {
                int iy = gy0t + y0 + ry + kh - 1, ix = gx0t + x0 + rx + kw - 1;
                if ((unsigned)iy < (unsigned)H && (unsigned)ix < (unsigned)W) {
                    #pragma unroll
                    for (int co = 0; co < 8; ++co) acc[ry][rx][co] += wv[co];
                }
            }
    }

    for (int cc = 0; cc < 8; ++cc) {          // 8 chunks of 4 base channels
        const int c0 = cc * 4;
        __syncthreads();                      // protect prior chunk's reads
        // stage weights for 12 planes: ci = (p+1)*32 + c0 + cl
        for (int j = tid; j < NPL * 288; j += 256) {
            int lp = j / 288;
            int r = j - lp * 288;
            int k = r >> 5, co = r & 31;
            int p = lp >> 2, cl = lp & 3;
            int ci = (p + 1) * 32 + c0 + cl;
            w_s[lp * 288 + k * 32 + co] = pw[(size_t)co * 1152 + ci * 9 + k];
        }
        // stage g planes: silu(P1), silu(P2), silu(P3) from bf16 t (zero-pad halo)
        for (int j = tid; j < 4 * GR * 34; j += 256) {
            int cl = j / (GR * 34);
            int r = j - cl * (GR * 34);
            int ly = r / 34, lx = r - ly * 34;
            int gy = gy0t + ly - 1, gx = gx0t + lx - 1;
            float v1 = 0.0f, v2 = 0.0f, v3 = 0.0f;
            if ((unsigned)gy < (unsigned)H && (unsigned)gx < (unsigned)W) {
                float tv = b2f(t_ws[(size_t)(b * C + c0 + cl) * HW + gy * W + gx]);
                float q2 = tv * tv - beta2;
                float q3 = tv * q2 - beta3 * tv;
                v1 = silu(tv); v2 = silu(q2); v3 = silu(q3);
            }
            int idx = ly * GC + lx;
            g_s[(0 * 4 + cl) * GP + idx] = v1;
            g_s[(1 * 4 + cl) * GP + idx] = v2;
            g_s[(2 * 4 + cl) * GP + idx] = v3;
        }
        __syncthreads();
        // main conv: per plane load 4x6 patch into regs, 9 taps x 8 co
        for (int lp = 0; lp < NPL; ++lp) {
            float patch[4][6];
            const float* gb = &g_s[lp * GP + y0 * GC + x0];
            #pragma unroll
            for (int r = 0; r < 4; ++r) {
                float4 a = *(const float4*)(gb + r * GC);
                float2 b2 = *(const float2*)(gb + r * GC + 4);
                patch[r][0] = a.x; patch[r][1] = a.y; patch[r][2] = a.z;
                patch[r][3] = a.w; patch[r][4] = b2.x; patch[r][5] = b2.y;
            }
            const float* wb = &w_s[lp * 288 + co0];
            #pragma unroll
            for (int k = 0; k < 9; ++k) {
                const int kh = k / 3, kw = k - kh * 3;
                float4 wa = *(const float4*)(wb + k * 32);
                float4 wc = *(const float4*)(wb + k * 32 + 4);
                float wv[8] = {wa.x, wa.y, wa.z, wa.w, wc.x, wc.y, wc.z, wc.w};
                #pragma unroll
                for (int ry = 0; ry < 2; ++ry)
                    #pragma unroll
                    for (int rx = 0; rx < 4; ++rx) {
                        const float gv = patch[ry + kh][rx + kw];
                        #pragma unroll
                        for (int co = 0; co < 8; ++co)
                            acc[ry][rx][co] = fmaf(gv, wv[co], acc[ry][rx][co]);
                    }
            }
        }
    }

    const float sc = scale[b];
    #pragma unroll
    for (int co = 0; co < 8; ++co) {
        const size_t base = (size_t)(b * CO + co0 + co) * HW;
        #pragma unroll
        for (int ry = 0; ry < 2; ++ry) {
            const int gy = gy0t + y0 + ry;
            float4 v;
            v.x = acc[ry][0][co] * sc; v.y = acc[ry][1][co] * sc;
            v.z = acc[ry][2][co] * sc; v.w = acc[ry][3][co] * sc;
            *(float4*)&out[base + (size_t)gy * W + gx0t + x0] = v;
        }
    }
}

extern "C" void kernel_launch(void* const* d_in, const int* in_sizes, int n_in,
                              void* d_out, int out_size, void* d_ws, size_t ws_size,
                              hipStream_t stream) {
    const float* x  = (const float*)d_in[0];
    const float* wg = (const float*)d_in[1];
    const float* pw = (const float*)d_in[2];
    const float* bw = (const float*)d_in[3];
    float* out = (float*)d_out;
    char* ws = (char*)d_ws;
    u16* t_ws     = (u16*)(ws + T_OFF);
    float* gate_x = (float*)(ws + GX_OFF);
    float* sc     = (float*)(ws + SC_OFF);
    float* Sk     = (float*)(ws + SK_OFF);

    stage1<<<dim3(B * C), 256, 0, stream>>>(x, t_ws, gate_x);
    gating<<<dim3(1), 256, 0, stream>>>(gate_x, wg, pw, sc, Sk, out + NTOT);
    conv_kernel<<<dim3(W / TW, H / TH, B), 256, 0, stream>>>(t_ws, pw, bw, sc, Sk, out);
}

// Round 2
// 313.563 us; speedup vs baseline: 2.0992x; 2.0992x over previous
//
#include <hip/hip_runtime.h>

typedef unsigned short u16;
typedef unsigned int u32;
typedef __attribute__((ext_vector_type(8))) short bf16x8;
typedef __attribute__((ext_vector_type(4))) float f32x4;

// Problem constants
static constexpr int B = 16, C = 32, H = 192, W = 192;
static constexpr int HW = H * W;              // 36864
static constexpr int E = 8;
static constexpr int CO = 32;
static constexpr long long NTOT = (long long)B * C * HW; // 18874368
static constexpr float SILU1 = 0.7310585786300049f;      // silu(1), P0 block

// Workspace layout (bytes)
static constexpr size_t T_OFF  = 0;                      // bf16 t, [b][y][x][c], NTOT
static constexpr size_t GX_OFF = (size_t)NTOT * 2;       // gate_x sums: 512 f
static constexpr size_t SC_OFF = GX_OFF + 512 * 4;       // scale: 16 f (pad 64B)
static constexpr size_t SK_OFF = SC_OFF + 64;            // Sk: 288 f [k][co]
static constexpr size_t SS_OFF = SK_OFF + 288 * 4;       // Ssum: 32 f (pad 128B)
static constexpr size_t WF_OFF = SS_OFF + 128;           // wfrag: 27648 bf16

__device__ inline u16 f2b(float f) {             // rne float->bf16 bits
    u32 u = __float_as_uint(f);
    return (u16)((u + 0x7fffu + ((u >> 16) & 1u)) >> 16);
}
__device__ inline float b2f(u16 r) { return __uint_as_float((u32)r << 16); }
__device__ inline float silu(float z) { return z / (1.0f + __expf(-z)); }

// ---------------- init: zero gate accumulator ------------------------------
__global__ void init_gate(float* __restrict__ gate_x) {
    gate_x[threadIdx.x] = 0.0f;
}

// ---------------- Stage 1: t=tanh(x) -> [b][y][x][c] bf16; gate partials ---
__global__ __launch_bounds__(192) void stage1(const float* __restrict__ x,
                                              u16* __restrict__ t_out,
                                              float* __restrict__ gate_x) {
    const int y = blockIdx.x, b = blockIdx.y;
    const int tx = threadIdx.x, lane = tx & 63, wv = tx >> 6;
    __shared__ float gred[C * 3];
    u16 tb[32];
    #pragma unroll
    for (int c = 0; c < 32; ++c) {
        float v = x[((size_t)(b * C + c) * H + y) * W + tx];
        tb[c] = f2b(tanhf(v));
        float s = v;
        #pragma unroll
        for (int off = 32; off > 0; off >>= 1) s += __shfl_down(s, off, 64);
        if (lane == 0) gred[c * 3 + wv] = s;
    }
    __syncthreads();
    if (tx < 32)
        atomicAdd(&gate_x[b * C + tx], gred[tx * 3] + gred[tx * 3 + 1] + gred[tx * 3 + 2]);
    uint4* o = (uint4*)(t_out + ((size_t)b * HW + (size_t)y * W + tx) * 32);
    const uint4* s4 = (const uint4*)tb;
    o[0] = s4[0]; o[1] = s4[1]; o[2] = s4[2]; o[3] = s4[3];
}

// ---------------- Stage 2: gating/loss + Sk/Ssum + bf16 weight fragments ---
// wfrag layout: [((p*9+tap)*2+half)][lane][8] bf16 per mfma B-frag:
//   B[k][n]: n = co = half*16 + (lane&15); k = ci_local = (lane>>4)*8 + e
__global__ __launch_bounds__(256) void gating(const float* __restrict__ gate_x,
                                              const float* __restrict__ wg,   // (32,8)
                                              const float* __restrict__ pw,   // (32,128,3,3)
                                              float* __restrict__ scale,
                                              float* __restrict__ SkG,
                                              float* __restrict__ SsumG,
                                              u16* __restrict__ wfrag,
                                              float* __restrict__ loss_out) {
    const int t = threadIdx.x;
    __shared__ float sks[288];
    // Sk[k][co] = sum_{ci<32} W[co][ci][k]
    for (int j = t; j < 288; j += 256) {
        int k = j >> 5, co = j & 31;
        float s = 0.0f;
        for (int ci = 0; ci < 32; ++ci) s += pw[(size_t)co * 1152 + ci * 9 + k];
        sks[j] = s; SkG[j] = s;
    }
    // weight fragments (bf16)
    for (int j = t; j < 27648; j += 256) {
        int e = j & 7, lane = (j >> 3) & 63, rest = j >> 9;
        int half = rest & 1, pt = rest >> 1;
        int p = pt / 9, tap = pt - p * 9;
        int co = half * 16 + (lane & 15);
        int ci = 32 + p * 32 + (lane >> 4) * 8 + e;
        wfrag[j] = f2b(pw[(size_t)co * 1152 + ci * 9 + tap]);
    }
    __syncthreads();
    if (t < 32) {
        float s = 0.0f;
        for (int k = 0; k < 9; ++k) s += sks[k * 32 + t];
        SsumG[t] = s;
    }
    __shared__ float gsh[B][E];
    if (t < B) {
        const float invHW = 1.0f / HW;
        float logits[E];
        for (int e = 0; e < E; ++e) {
            float s = 0.0f;
            for (int c = 0; c < C; ++c) s += (gate_x[t * C + c] * invHW) * wg[c * E + e];
            logits[e] = s;
        }
        float m = logits[0];
        for (int e = 1; e < E; ++e) m = fmaxf(m, logits[e]);
        float p[E], sum = 0.0f;
        for (int e = 0; e < E; ++e) { p[e] = expf(logits[e] - m); sum += p[e]; }
        for (int e = 0; e < E; ++e) p[e] /= sum;
        int i0 = 0; float v0 = p[0];
        for (int e = 1; e < E; ++e) if (p[e] > v0) { v0 = p[e]; i0 = e; }
        int i1 = -1; float v1 = -1.0f;
        for (int e = 0; e < E; ++e) { if (e == i0) continue; if (p[e] > v1) { v1 = p[e]; i1 = e; } }
        const float denom = v0 + v1 + 1e-6f;
        const float g0 = v0 / denom, g1 = v1 / denom;
        for (int e = 0; e < E; ++e) gsh[t][e] = 0.0f;
        gsh[t][i0] = g0; gsh[t][i1] = g1;
        scale[t] = g0 + g1;
    }
    __syncthreads();
    __shared__ float impsh[E], loadsh[E];
    if (t < E) {
        float imp = 0.0f, ld = 0.0f;
        for (int b = 0; b < B; ++b) {
            float g = gsh[b][t];
            imp += g;
            if (g > 0.0f) ld += 1.0f;
        }
        impsh[t] = imp; loadsh[t] = ld;
    }
    __syncthreads();
    if (t == 0) {
        float mi = 0.0f, ml = 0.0f;
        for (int e = 0; e < E; ++e) { mi += impsh[e]; ml += loadsh[e]; }
        mi *= (1.0f / E); ml *= (1.0f / E);
        float vi = 0.0f, vl = 0.0f;
        for (int e = 0; e < E; ++e) {
            float di = impsh[e] - mi, dl = loadsh[e] - ml;
            vi += di * di; vl += dl * dl;
        }
        vi *= (1.0f / (E - 1)); vl *= (1.0f / (E - 1));
        *loss_out = (vi / (mi * mi + 1e-10f) + vl / (ml * ml + 1e-10f)) * 0.01f;
    }
}

// ---------------- Stage 3: MFMA implicit-GEMM conv -------------------------
// Block: 16x16 spatial tile, all 32 co, 256 thr = 4 waves.
// Wave w: rows 4w..4w+3 (m-tiles a=0..3, m = x in tile), co split in 2 halves.
// K = 3 chunks (P1,P2,P3 silu'd) x 9 taps x 32 ci; A from LDS gtile [pix][ci].
static constexpr int GSTR = 40;                 // bf16 stride per pixel (32+8 pad)
__global__ __launch_bounds__(256) void conv_mfma(const u16* __restrict__ t_ws,
                                                 const u16* __restrict__ wfrag,
                                                 const float* __restrict__ beta_w,
                                                 const float* __restrict__ scale,
                                                 const float* __restrict__ Sk,
                                                 const float* __restrict__ Ssum,
                                                 float* __restrict__ out) {
    __shared__ __align__(16) u16 gtile[324 * GSTR];   // 18x18 pixels x 40 bf16 = 25920 B
    const int b = blockIdx.z;
    const int gx0 = blockIdx.x << 4, gy0 = blockIdx.y << 4;
    const int tid = threadIdx.x;
    const int w = tid >> 6, lane = tid & 63, q = lane >> 4, ml = lane & 15;
    const float beta2 = 2.25f * beta_w[1];
    const float beta3 = (300.0f / 9.0f) * beta_w[2];
    const u16* tb = t_ws + (size_t)b * HW * 32;

    f32x4 acc[4][2];
    #pragma unroll
    for (int a = 0; a < 4; ++a)
        #pragma unroll
        for (int h = 0; h < 2; ++h)
            acc[a][h] = (f32x4){0.0f, 0.0f, 0.0f, 0.0f};

    #pragma unroll
    for (int p = 0; p < 3; ++p) {
        __syncthreads();                         // protect prior chunk reads
        for (int j = tid; j < 1296; j += 256) {  // 324 pixels x 4 quarters
            int pix = j >> 2, qq = j & 3;
            int py = pix / 18, px = pix - py * 18;
            int gy = gy0 + py - 1, gx = gx0 + px - 1;
            uint4 res;
            if ((unsigned)gy < (unsigned)H && (unsigned)gx < (unsigned)W) {
                uint4 val = *(const uint4*)(tb + (((size_t)(gy * W + gx)) << 5) + (qq << 3));
                u16 r8[8];
                const u16* tv = (const u16*)&val;
                #pragma unroll
                for (int e = 0; e < 8; ++e) {
                    float tt = b2f(tv[e]);
                    float u;
                    if (p == 0) u = tt;
                    else if (p == 1) u = tt * tt - beta2;
                    else { float p2v = tt * tt - beta2; u = tt * p2v - beta3 * tt; }
                    r8[e] = f2b(silu(u));
                }
                res = *(const uint4*)r8;
            } else {
                res = make_uint4(0u, 0u, 0u, 0u);  // zero-pad halo
            }
            *(uint4*)&gtile[pix * GSTR + (qq << 3)] = res;
        }
        __syncthreads();
        const u16* wf = wfrag + (size_t)p * 9 * 2 * 64 * 8;
        #pragma unroll
        for (int tap = 0; tap < 9; ++tap) {
            const int dy = tap / 3 - 1, dx = tap % 3 - 1;
            bf16x8 b0 = *(const bf16x8*)(wf + ((size_t)(tap * 2 + 0) * 64 + lane) * 8);
            bf16x8 b1 = *(const bf16x8*)(wf + ((size_t)(tap * 2 + 1) * 64 + lane) * 8);
            #pragma unroll
            for (int a = 0; a < 4; ++a) {
                const bf16x8 af = *(const bf16x8*)
                    &gtile[(((w << 2) + a + dy + 1) * 18 + (ml + dx + 1)) * GSTR + (q << 3)];
                acc[a][0] = __builtin_amdgcn_mfma_f32_16x16x32_bf16(af, b0, acc[a][0], 0, 0, 0);
                acc[a][1] = __builtin_amdgcn_mfma_f32_16x16x32_bf16(af, b1, acc[a][1], 0, 0, 0);
            }
        }
    }

    // Epilogue: + P0 bias (border-aware), * scale[b], store.
    // D layout: row m = q*4+r -> x = gx0+q*4+r ; col = co = half*16+ml ; y = gy0+4w+a
    const float sc = scale[b];
    const bool interior = (blockIdx.x > 0) && (blockIdx.x < 11) &&
                          (blockIdx.y > 0) && (blockIdx.y < 11);
    #pragma unroll
    for (int half = 0; half < 2; ++half) {
        const int co = half * 16 + ml;
        const float bfull = SILU1 * Ssum[co];
        #pragma unroll
        for (int a = 0; a < 4; ++a) {
            const int y = gy0 + (w << 2) + a;
            float ov[4];
            #pragma unroll
            for (int r = 0; r < 4; ++r) {
                float bias = bfull;
                if (!interior) {
                    const int xg = gx0 + (q << 2) + r;
                    bias = 0.0f;
                    #pragma unroll
                    for (int k = 0; k < 9; ++k) {
                        int yy = y + k / 3 - 1, xx = xg + k % 3 - 1;
                        if ((unsigned)yy < (unsigned)H && (unsigned)xx < (unsigned)W)
                            bias += Sk[k * 32 + co];
                    }
                    bias *= SILU1;
                }
                ov[r] = (acc[a][half][r] + bias) * sc;
            }
            *(float4*)&out[((size_t)(b * CO + co) * H + y) * W + gx0 + (q << 2)] = *(float4*)ov;
        }
    }
}

extern "C" void kernel_launch(void* const* d_in, const int* in_sizes, int n_in,
                              void* d_out, int out_size, void* d_ws, size_t ws_size,
                              hipStream_t stream) {
    const float* x  = (const float*)d_in[0];
    const float* wg = (const float*)d_in[1];
    const float* pw = (const float*)d_in[2];
    const float* bw = (const float*)d_in[3];
    float* out = (float*)d_out;
    char* ws = (char*)d_ws;
    u16*   t_ws   = (u16*)(ws + T_OFF);
    float* gate_x = (float*)(ws + GX_OFF);
    float* sc     = (float*)(ws + SC_OFF);
    float* Sk     = (float*)(ws + SK_OFF);
    float* Ssum   = (float*)(ws + SS_OFF);
    u16*   wfrag  = (u16*)(ws + WF_OFF);

    init_gate<<<dim3(1), 512, 0, stream>>>(gate_x);
    stage1<<<dim3(H, B), 192, 0, stream>>>(x, t_ws, gate_x);
    gating<<<dim3(1), 256, 0, stream>>>(gate_x, wg, pw, sc, Sk, Ssum, wfrag, out + NTOT);
    conv_mfma<<<dim3(12, 12, B), 256, 0, stream>>>(t_ws, wfrag, bw, sc, Sk, Ssum, out);
}